// Round 11
// baseline (508.086 us; speedup 1.0000x reference)
//
#include <hip/hip_runtime.h>
#include <hip/hip_bf16.h>
#include <math.h>

// Model dims
#define BB 8
#define TT 1024
#define DD 256
#define HH 512
#define NN 16
#define RR 8
#define OUT_LEN 96
#define IN_DIM 32
#define MM (BB*TT)   // 8192 rows

// scan chunking (validated R10)
#define SC 32
#define CC (TT/SC)   // 32

typedef unsigned short u16;
typedef unsigned int u32;
typedef __attribute__((ext_vector_type(8))) short short8;
typedef __attribute__((ext_vector_type(8))) unsigned short u16x8;
typedef __attribute__((ext_vector_type(4))) float float4v;

__device__ __forceinline__ u16 f2bf(float f) {
    __hip_bfloat16 h = __float2bfloat16(f);
    return *(u16*)&h;
}
__device__ __forceinline__ float bf2f(u16 u) {
    u32 v = ((u32)u) << 16;
    return *(float*)&v;
}

#define GLD_LDS16(src, dst) __builtin_amdgcn_global_load_lds( \
    (const __attribute__((address_space(1))) void*)(src),     \
    (__attribute__((address_space(3))) void*)(dst), 16, 0, 0)

// ---------------------------------------------------------------------------
// Embedding + PE + layer-0 LN (blocks 0..MM-1) | weight bf16 cvt (rest).
// (validated R10)
// ---------------------------------------------------------------------------
__global__ __launch_bounds__(256) void embed_ln_cvt_kernel(
    const float* __restrict__ x, const float* __restrict__ emb_w,
    const float* __restrict__ emb_b,
    const float* __restrict__ g, const float* __restrict__ b,
    float* __restrict__ h, u16* __restrict__ lnout,
    const float* __restrict__ w_in, u16* __restrict__ wbf_in,
    const float* __restrict__ w_out, u16* __restrict__ wbf_out, int nw)
{
    int bid = blockIdx.x;
    if (bid >= MM) {
        int i = (bid - MM) * 256 + threadIdx.x;
        if (i < nw) wbf_in[i] = f2bf(w_in[i]);
        else        wbf_out[i - nw] = f2bf(w_out[i - nw]);
        return;
    }

    int bt = bid;
    int d  = threadIdx.x;
    int t  = bt & (TT - 1);

    __shared__ float xs[IN_DIM];
    __shared__ float red[4], red2[4];
    if (threadIdx.x < IN_DIM) xs[threadIdx.x] = x[bt * IN_DIM + threadIdx.x];
    __syncthreads();

    const float* w = emb_w + d * IN_DIM;
    float acc = emb_b[d];
#pragma unroll
    for (int i = 0; i < IN_DIM; i++) acc = fmaf(xs[i], w[i], acc);

    int i2 = d & ~1;
    float div = expf(-(float)i2 * (logf(10000.0f) / (float)DD));
    float arg = (float)t * div;
    float pe = (d & 1) ? cosf(arg) : sinf(arg);
    float val = acc + pe;
    h[bt * DD + d] = val;

    float s = val;
#pragma unroll
    for (int o = 32; o > 0; o >>= 1) s += __shfl_down(s, o);
    int lane = d & 63, wave = d >> 6;
    if (lane == 0) red[wave] = s;
    __syncthreads();
    float mean = (red[0] + red[1] + red[2] + red[3]) * (1.0f / DD);

    float c = val - mean;
    float s2 = c * c;
#pragma unroll
    for (int o = 32; o > 0; o >>= 1) s2 += __shfl_down(s2, o);
    if (lane == 0) red2[wave] = s2;
    __syncthreads();
    float var = (red2[0] + red2[1] + red2[2] + red2[3]) * (1.0f / DD);

    lnout[bt * DD + d] = f2bf(c * rsqrtf(var + 1e-5f) * g[d] + b[d]);
}

// ---------------------------------------------------------------------------
// bf16 MFMA NT GEMM. NEW: BK=128 (32 MFMA per barrier pair, halved drains).
// LDS [k-octet][row][8 bf16]; fragments loaded per-kk to bound VGPRs.
// ---------------------------------------------------------------------------
template<int BM, int BN, int OUT_BF16>
__global__ __launch_bounds__(256) void gemm_bf16(
    const u16* __restrict__ A, const u16* __restrict__ B,
    void* __restrict__ Cv, int M, int N, int K, int addC)
{
    constexpr int BK = 128;
    constexpr int MT = BM / 32;
    constexpr int NT = BN / 32;
    static_assert(BN == 64, "B staging assumes BN==64");

    __shared__ __align__(16) u16 Al[16][BM][8];   // BM=128: 32 KB
    __shared__ __align__(16) u16 Bl[16][BN][8];   // 16 KB

    const int tid = threadIdx.x;
    const int bm = blockIdx.y * BM;
    const int bn = blockIdx.x * BN;
    const int wid = tid >> 6, lane = tid & 63;
    const int wm = wid >> 1, wn = wid & 1;
    const int lq = lane >> 4, lm = lane & 15;

    float4v acc[MT][NT];
#pragma unroll
    for (int i = 0; i < MT; i++)
#pragma unroll
        for (int j = 0; j < NT; j++) acc[i][j] = (float4v){0.f, 0.f, 0.f, 0.f};

    for (int k0 = 0; k0 < K; k0 += BK) {
#pragma unroll
        for (int it = 0; it < (16 * BM) / 256; it++) {
            int c = it * 256 + tid;
            int q = c / BM, row = c % BM;
            GLD_LDS16(A + (size_t)(bm + row) * K + k0 + q * 8, &Al[q][row][0]);
        }
#pragma unroll
        for (int it = 0; it < (16 * BN) / 256; it++) {
            int c = it * 256 + tid;
            int q = c / BN, row = c % BN;
            GLD_LDS16(B + (size_t)(bn + row) * K + k0 + q * 8, &Bl[q][row][0]);
        }
        __syncthreads();

#pragma unroll
        for (int kk = 0; kk < 4; kk++) {
            short8 af[MT], bf[NT];
#pragma unroll
            for (int mt = 0; mt < MT; mt++)
                af[mt] = *(const short8*)&Al[kk * 4 + lq][wm * (BM / 2) + mt * 16 + lm][0];
#pragma unroll
            for (int nt = 0; nt < NT; nt++)
                bf[nt] = *(const short8*)&Bl[kk * 4 + lq][wn * (BN / 2) + nt * 16 + lm][0];
#pragma unroll
            for (int mt = 0; mt < MT; mt++)
#pragma unroll
                for (int nt = 0; nt < NT; nt++)
                    acc[mt][nt] = __builtin_amdgcn_mfma_f32_16x16x32_bf16(
                        af[mt], bf[nt], acc[mt][nt], 0, 0, 0);
        }
        __syncthreads();
    }

#pragma unroll
    for (int mt = 0; mt < MT; mt++)
#pragma unroll
        for (int nt = 0; nt < NT; nt++) {
            int row0 = bm + wm * (BM / 2) + mt * 16 + lq * 4;
            int col  = bn + wn * (BN / 2) + nt * 16 + lm;
#pragma unroll
            for (int r = 0; r < 4; r++) {
                float vv = acc[mt][nt][r];
                if (OUT_BF16) {
                    ((u16*)Cv)[(size_t)(row0 + r) * N + col] = f2bf(vv);
                } else {
                    float* cp = (float*)Cv + (size_t)(row0 + r) * N + col;
                    if (addC) vv += *cp;
                    *cp = vv;
                }
            }
        }
}

// ---------------------------------------------------------------------------
// Out-projection GEMM + residual + next-layer LN. NEW: BK=128 (4 K-iters).
// LDS 8+64=72 KB (grid is 1 block/CU anyway).
// ---------------------------------------------------------------------------
__global__ __launch_bounds__(256) void gemm2_ln(
    const u16* __restrict__ A, const u16* __restrict__ B,
    float* __restrict__ h,
    const float* __restrict__ g, const float* __restrict__ bb,
    u16* __restrict__ lnout, int doLN)
{
    constexpr int BM = 32;
    __shared__ __align__(16) u16 Al[16][BM][8];   // 8 KB
    __shared__ __align__(16) u16 Bl[16][256][8];  // 64 KB
    __shared__ float rs[2][BM], qs[2][BM];

    const int tid = threadIdx.x;
    const int bm = blockIdx.x * BM;
    const int wid = tid >> 6, lane = tid & 63;
    const int wm = wid >> 1, wn = wid & 1;
    const int lq = lane >> 4, lm = lane & 15;

    float4v acc[8];
#pragma unroll
    for (int j = 0; j < 8; j++) acc[j] = (float4v){0.f, 0.f, 0.f, 0.f};

    for (int k0 = 0; k0 < 512; k0 += 128) {
#pragma unroll
        for (int it = 0; it < 2; it++) {   // A: 16*32 = 512 chunks
            int c = it * 256 + tid;
            int q = c >> 5, row = c & 31;
            GLD_LDS16(A + (size_t)(bm + row) * 512 + k0 + q * 8, &Al[q][row][0]);
        }
#pragma unroll
        for (int it = 0; it < 16; it++) {  // B: 16*256 = 4096 chunks
            int c = it * 256 + tid;
            int q = c >> 8, row = c & 255;
            GLD_LDS16(B + (size_t)row * 512 + k0 + q * 8, &Bl[q][row][0]);
        }
        __syncthreads();

#pragma unroll
        for (int kk = 0; kk < 4; kk++) {
            short8 af, bf[8];
            af = *(const short8*)&Al[kk * 4 + lq][wm * 16 + lm][0];
#pragma unroll
            for (int nt = 0; nt < 8; nt++)
                bf[nt] = *(const short8*)&Bl[kk * 4 + lq][wn * 128 + nt * 16 + lm][0];
#pragma unroll
            for (int nt = 0; nt < 8; nt++)
                acc[nt] = __builtin_amdgcn_mfma_f32_16x16x32_bf16(
                    af, bf[nt], acc[nt], 0, 0, 0);
        }
        __syncthreads();
    }

    float val[4][8];
    float s1[4] = {0.f, 0.f, 0.f, 0.f}, s2[4] = {0.f, 0.f, 0.f, 0.f};
#pragma unroll
    for (int r = 0; r < 4; r++) {
        int row = bm + wm * 16 + lq * 4 + r;
#pragma unroll
        for (int nt = 0; nt < 8; nt++) {
            int col = wn * 128 + nt * 16 + lm;
            float v = acc[nt][r] + h[(size_t)row * DD + col];
            val[r][nt] = v;
            s1[r] += v;
            s2[r] = fmaf(v, v, s2[r]);
            h[(size_t)row * DD + col] = v;
        }
    }
#pragma unroll
    for (int r = 0; r < 4; r++) {
#pragma unroll
        for (int o = 1; o < 16; o <<= 1) {
            s1[r] += __shfl_xor(s1[r], o);
            s2[r] += __shfl_xor(s2[r], o);
        }
    }
    if (lm == 0) {
#pragma unroll
        for (int r = 0; r < 4; r++) {
            rs[wn][wm * 16 + lq * 4 + r] = s1[r];
            qs[wn][wm * 16 + lq * 4 + r] = s2[r];
        }
    }
    __syncthreads();

    if (doLN) {
#pragma unroll
        for (int r = 0; r < 4; r++) {
            int i = wm * 16 + lq * 4 + r;
            int row = bm + i;
            float mean = (rs[0][i] + rs[1][i]) * (1.0f / DD);
            float var  = (qs[0][i] + qs[1][i]) * (1.0f / DD) - mean * mean;
            float rstd = rsqrtf(var + 1e-5f);
#pragma unroll
            for (int nt = 0; nt < 8; nt++) {
                int col = wn * 128 + nt * 16 + lm;
                lnout[(size_t)row * DD + col] =
                    f2bf((val[r][nt] - mean) * rstd * g[col] + bb[col]);
            }
        }
    }
}

// ---------------------------------------------------------------------------
// Fused depthwise conv(k=3,pad1)+SiLU + dt1 (validated R7-R10)
// ---------------------------------------------------------------------------
__global__ __launch_bounds__(256) void conv_dt1_kernel(
    const u16* __restrict__ v, const float* __restrict__ cwg,
    const float* __restrict__ w1g, const float* __restrict__ b1g,
    u16* __restrict__ vsb, float* __restrict__ dtr)
{
    __shared__ float w1s[RR * 2 * 256];
    int tid = threadIdx.x;
    {
        int lane = tid & 63, rc = tid >> 6;
#pragma unroll
        for (int i = 0; i < 4; i++) {
            int rci = rc + i * 4;
            int r = rci >> 1, jc = rci & 1;
            float4 wv = *(const float4*)(w1g + r * HH + lane * 8 + jc * 4);
            *(float4*)&w1s[rci * 256 + lane * 4] = wv;
        }
    }
    __syncthreads();

    int wave = tid >> 6, lane = tid & 63;
    int m = blockIdx.x * 4 + wave;
    int t = m & (TT - 1);
    int h0 = lane * 8;

    const u16* vrow = v + (size_t)m * HH + h0;
    u16x8 x0 = *(const u16x8*)vrow;
    u16x8 xm = (t > 0)      ? *(const u16x8*)(vrow - HH) : (u16x8)(0);
    u16x8 xp = (t < TT - 1) ? *(const u16x8*)(vrow + HH) : (u16x8)(0);

    const float* wp = cwg + h0 * 3;
    float a[8];
    u16x8 o;
#pragma unroll
    for (int j = 0; j < 8; j++) {
        float s = wp[j * 3] * bf2f(xm[j]);
        s = fmaf(wp[j * 3 + 1], bf2f(x0[j]), s);
        s = fmaf(wp[j * 3 + 2], bf2f(xp[j]), s);
        s = s / (1.0f + __expf(-s));
        a[j] = s;
        o[j] = f2bf(s);
    }
    *(u16x8*)(vsb + (size_t)m * HH + h0) = o;

    float acc[RR];
#pragma unroll
    for (int r = 0; r < RR; r++) {
        float4 wlo = *(const float4*)&w1s[(r * 2 + 0) * 256 + lane * 4];
        float4 whi = *(const float4*)&w1s[(r * 2 + 1) * 256 + lane * 4];
        float s = a[0] * wlo.x;
        s = fmaf(a[1], wlo.y, s);
        s = fmaf(a[2], wlo.z, s);
        s = fmaf(a[3], wlo.w, s);
        s = fmaf(a[4], whi.x, s);
        s = fmaf(a[5], whi.y, s);
        s = fmaf(a[6], whi.z, s);
        s = fmaf(a[7], whi.w, s);
        acc[r] = s;
    }
#pragma unroll
    for (int r = 0; r < RR; r++) {
#pragma unroll
        for (int o2 = 1; o2 < 64; o2 <<= 1) acc[r] += __shfl_xor(acc[r], o2);
    }
    if (lane == 0) {
#pragma unroll
        for (int r = 0; r < RR; r++) acc[r] = fmaxf(acc[r] + b1g[r], 0.0f);
        *(float4*)(dtr + (size_t)m * RR)     = make_float4(acc[0], acc[1], acc[2], acc[3]);
        *(float4*)(dtr + (size_t)m * RR + 4) = make_float4(acc[4], acc[5], acc[6], acc[7]);
    }
}

// ---------------------------------------------------------------------------
__device__ __forceinline__ float softplus_f(float s) {
    return (s > 20.0f) ? s : __logf(1.0f + __expf(s));
}

// ---------------------------------------------------------------------------
// Scan pass1 (validated R10; bf16 Lst)
// ---------------------------------------------------------------------------
__global__ __launch_bounds__(256) void scan_pass1(
    const u16* __restrict__ vs, const float* __restrict__ dtr,
    const float* __restrict__ dt2_w, const float* __restrict__ dt2_b,
    const float* __restrict__ A_p,
    u16* __restrict__ Lst, float* __restrict__ sdt)
{
    int h = blockIdx.x * 256 + threadIdx.x;
    int c = blockIdx.y;
    int b = blockIdx.z;

    float A[NN], invA[NN], st[NN];
    const float* ap = A_p + h * NN;
#pragma unroll
    for (int n = 0; n < NN; n++) {
        float a = -__expf(ap[n]);
        A[n] = a; invA[n] = 1.0f / a; st[n] = 0.0f;
    }
    float w2[RR];
#pragma unroll
    for (int r = 0; r < RR; r++) w2[r] = dt2_w[h * RR + r];
    float b2 = dt2_b[h];

    const u16*   vbase = vs  + ((size_t)b * TT + (size_t)c * SC) * HH + h;
    const float* drow  = dtr + ((size_t)b * TT + (size_t)c * SC) * RR;

    float dr[RR];
#pragma unroll
    for (int r = 0; r < RR; r++) dr[r] = drow[r];

    float s_dt = 0.0f;
#pragma unroll 2
    for (int t = 0; t < SC; t++) {
        float drn[RR];
        if (t + 1 < SC) {
#pragma unroll
            for (int r = 0; r < RR; r++) drn[r] = drow[(t + 1) * RR + r];
        }
        float s = b2;
#pragma unroll
        for (int r = 0; r < RR; r++) s = fmaf(dr[r], w2[r], s);
        float dt = softplus_f(s);
        float xv = bf2f(vbase[(size_t)t * HH]);
        s_dt += dt;
#pragma unroll
        for (int n = 0; n < NN; n++) {
            float e  = __expf(A[n] * dt);
            float dB = (e - 1.0f) * invA[n] * dt;
            st[n] = fmaf(e, st[n], dB * xv);
        }
#pragma unroll
        for (int r = 0; r < RR; r++) dr[r] = drn[r];
    }

    size_t base = (((size_t)c * BB + b) * HH + h) * NN;
    u16x8 lo, hi;
#pragma unroll
    for (int n = 0; n < 8; n++) { lo[n] = f2bf(st[n]); hi[n] = f2bf(st[n + 8]); }
    *(u16x8*)(Lst + base)     = lo;
    *(u16x8*)(Lst + base + 8) = hi;
    sdt[((size_t)c * BB + b) * HH + h] = s_dt;
}

// ---------------------------------------------------------------------------
// Carry. NEW: batched independent loads + upfront exps; the serial chain
// reduces to 32 dependent FMAs in registers (was 32 x ~300-cyc load chain).
// ---------------------------------------------------------------------------
__global__ __launch_bounds__(256) void scan_carry(
    const float* __restrict__ A_p, const float* __restrict__ sdt,
    u16* __restrict__ Lst)
{
    int i = blockIdx.x * 256 + threadIdx.x;   // (b*HH+h)*NN+n
    int n  = i & (NN - 1);
    int bh = i >> 4;
    int h  = bh & (HH - 1);
    int b  = bh >> 9;

    float A = -__expf(A_p[h * NN + n]);

    float P[CC], L[CC];
#pragma unroll
    for (int c = 0; c < CC; c++) {
        size_t sidx = ((size_t)c * BB + b) * HH + h;
        P[c] = sdt[sidx];
        L[c] = bf2f(Lst[sidx * NN + n]);
    }
#pragma unroll
    for (int c = 0; c < CC; c++) P[c] = __expf(A * P[c]);

    float E = 0.0f;
#pragma unroll
    for (int c = 0; c < CC; c++) {
        size_t sidx = ((size_t)c * BB + b) * HH + h;
        Lst[sidx * NN + n] = f2bf(E);
        E = fmaf(P[c], E, L[c]);
    }
}

// ---------------------------------------------------------------------------
// Scan pass2 (validated R10; bf16 carry)
// ---------------------------------------------------------------------------
__global__ __launch_bounds__(256) void scan_pass2(
    const u16* __restrict__ vs,
    const float* __restrict__ dtr,
    const float* __restrict__ dt2_w,
    const float* __restrict__ dt2_b,
    const float* __restrict__ A_p, const float* __restrict__ D_p,
    const u16* __restrict__ carry,
    u16* __restrict__ y)
{
    int h = blockIdx.x * 256 + threadIdx.x;
    int c = blockIdx.y;
    int b = blockIdx.z;

    float A[NN], invA[NN], Ap[NN], st[NN];
    const float* app = A_p + h * NN;
    size_t cbase = (((size_t)c * BB + b) * HH + h) * NN;
    {
        u16x8 lo = *(const u16x8*)(carry + cbase);
        u16x8 hi = *(const u16x8*)(carry + cbase + 8);
#pragma unroll
        for (int n = 0; n < 8; n++) { st[n] = bf2f(lo[n]); st[n + 8] = bf2f(hi[n]); }
    }
#pragma unroll
    for (int n = 0; n < NN; n++) {
        float apv = app[n];
        Ap[n] = apv;
        float a = -__expf(apv);
        A[n] = a; invA[n] = 1.0f / a;
    }
    float w2[RR];
#pragma unroll
    for (int r = 0; r < RR; r++) w2[r] = dt2_w[h * RR + r];
    float b2 = dt2_b[h];
    float Dp = D_p[h];

    const u16*   vbase = vs  + ((size_t)b * TT + (size_t)c * SC) * HH + h;
    const float* drow  = dtr + ((size_t)b * TT + (size_t)c * SC) * RR;
    u16*         ybase = y   + ((size_t)b * TT + (size_t)c * SC) * HH + h;

    float dr[RR];
#pragma unroll
    for (int r = 0; r < RR; r++) dr[r] = drow[r];

#pragma unroll 2
    for (int t = 0; t < SC; t++) {
        float drn[RR];
        if (t + 1 < SC) {
#pragma unroll
            for (int r = 0; r < RR; r++) drn[r] = drow[(t + 1) * RR + r];
        }
        float s = b2;
#pragma unroll
        for (int r = 0; r < RR; r++) s = fmaf(dr[r], w2[r], s);
        float dt = softplus_f(s);
        float xv = bf2f(vbase[(size_t)t * HH]);
        float acc = Dp * xv;
#pragma unroll
        for (int n = 0; n < NN; n++) {
            float e  = __expf(A[n] * dt);
            float dB = (e - 1.0f) * invA[n] * dt;
            st[n] = fmaf(e, st[n], dB * xv);
            acc = fmaf(st[n], Ap[n], acc);
        }
        ybase[(size_t)t * HH] = f2bf(acc);
#pragma unroll
        for (int r = 0; r < RR; r++) dr[r] = drn[r];
    }
}

// ---------------------------------------------------------------------------
// Head: final LN on last token, head1+silu, head2. One block per batch.
// ---------------------------------------------------------------------------
__global__ __launch_bounds__(256) void head_kernel(
    const float* __restrict__ h,
    const float* __restrict__ fg, const float* __restrict__ fb,
    const float* __restrict__ w1, const float* __restrict__ b1,
    const float* __restrict__ w2, const float* __restrict__ b2,
    float* __restrict__ out)
{
    int b = blockIdx.x;
    int d = threadIdx.x;
    __shared__ float hn[DD], s1[DD];
    __shared__ float red[4];

    float v = h[((size_t)b * TT + (TT - 1)) * DD + d];

    float s = v;
#pragma unroll
    for (int o = 32; o > 0; o >>= 1) s += __shfl_down(s, o);
    int lane = d & 63, wave = d >> 6;
    if (lane == 0) red[wave] = s;
    __syncthreads();
    float mean = (red[0] + red[1] + red[2] + red[3]) * (1.0f / DD);
    __syncthreads();

    float c = v - mean;
    float s2 = c * c;
#pragma unroll
    for (int o = 32; o > 0; o >>= 1) s2 += __shfl_down(s2, o);
    if (lane == 0) red[wave] = s2;
    __syncthreads();
    float var = (red[0] + red[1] + red[2] + red[3]) * (1.0f / DD);

    hn[d] = c * rsqrtf(var + 1e-5f) * fg[d] + fb[d];
    __syncthreads();

    float a1 = b1[d];
    const float* w1r = w1 + d * DD;
#pragma unroll 8
    for (int k = 0; k < DD; k++) a1 = fmaf(hn[k], w1r[k], a1);
    s1[d] = a1 / (1.0f + __expf(-a1));
    __syncthreads();

    if (d < OUT_LEN) {
        float a2 = b2[d];
        const float* w2r = w2 + d * DD;
#pragma unroll 8
        for (int k = 0; k < DD; k++) a2 = fmaf(s1[k], w2r[k], a2);
        out[b * OUT_LEN + d] = a2;
    }
}

// ---------------------------------------------------------------------------
extern "C" void kernel_launch(void* const* d_in, const int* in_sizes, int n_in,
                              void* d_out, int out_size, void* d_ws, size_t ws_size,
                              hipStream_t stream)
{
    (void)in_sizes; (void)n_in; (void)out_size; (void)ws_size;

    const float* x       = (const float*)d_in[0];
    const float* emb_w   = (const float*)d_in[1];
    const float* emb_b   = (const float*)d_in[2];
    const float* norm_g  = (const float*)d_in[3];
    const float* norm_b  = (const float*)d_in[4];
    const float* in_w    = (const float*)d_in[5];
    const float* conv_w  = (const float*)d_in[6];
    const float* A_p     = (const float*)d_in[7];
    const float* D_p     = (const float*)d_in[8];
    const float* dt1_w   = (const float*)d_in[9];
    const float* dt1_b   = (const float*)d_in[10];
    const float* dt2_w   = (const float*)d_in[11];
    const float* dt2_b   = (const float*)d_in[12];
    const float* out_w   = (const float*)d_in[13];
    const float* final_g = (const float*)d_in[14];
    const float* final_b = (const float*)d_in[15];
    const float* head1_w = (const float*)d_in[16];
    const float* head1_b = (const float*)d_in[17];
    const float* head2_w = (const float*)d_in[18];
    const float* head2_b = (const float*)d_in[19];
    float* outp = (float*)d_out;

    char* ws = (char*)d_ws;
    float* h     = (float*)ws;                ws += (size_t)MM * DD * 4;   // fp32 residual
    u16*   vbf   = (u16*)ws;                  ws += (size_t)MM * HH * 2;   // gemm1 out
    u16*   vsb   = (u16*)ws;                  ws += (size_t)MM * HH * 2;   // conv+silu
    u16*   ybf   = (u16*)ws;                  ws += (size_t)MM * HH * 2;   // scan y
    u16*   lnbuf = (u16*)ws;                  ws += (size_t)MM * DD * 2;   // LN out
    float* dtr   = (float*)ws;                ws += (size_t)MM * RR * 4;
    u16*   Lst   = (u16*)ws;                  ws += (size_t)CC * BB * HH * NN * 2;  // bf16
    float* sdt   = (float*)ws;                ws += (size_t)CC * BB * HH * 4;
    u16*   wbf_in  = (u16*)ws;                ws += (size_t)4 * HH * DD * 2;
    u16*   wbf_out = (u16*)ws;                ws += (size_t)4 * DD * HH * 2;

    const int NW = 4 * HH * DD;
    embed_ln_cvt_kernel<<<MM + (2 * NW) / 256, 256, 0, stream>>>(
        x, emb_w, emb_b, norm_g, norm_b, h, lnbuf,
        in_w, wbf_in, out_w, wbf_out, NW);

    for (int l = 0; l < 4; l++) {
        gemm_bf16<128, 64, 1><<<dim3(HH / 64, MM / 128), 256, 0, stream>>>(
            lnbuf, wbf_in + (size_t)l * HH * DD, vbf, MM, HH, DD, 0);
        conv_dt1_kernel<<<MM / 4, 256, 0, stream>>>(
            vbf, conv_w + (size_t)l * HH * 3,
            dt1_w + (size_t)l * RR * HH, dt1_b + l * RR, vsb, dtr);

        scan_pass1<<<dim3(HH / 256, CC, BB), 256, 0, stream>>>(
            vsb, dtr, dt2_w + (size_t)l * HH * RR, dt2_b + l * HH,
            A_p + (size_t)l * HH * NN, Lst, sdt);
        scan_carry<<<(BB * HH * NN) / 256, 256, 0, stream>>>(
            A_p + (size_t)l * HH * NN, sdt, Lst);
        scan_pass2<<<dim3(HH / 256, CC, BB), 256, 0, stream>>>(
            vsb, dtr, dt2_w + (size_t)l * HH * RR, dt2_b + l * HH,
            A_p + (size_t)l * HH * NN, D_p + l * HH, Lst, ybf);

        const float* g_next = (l < 3) ? (norm_g + (l + 1) * DD) : final_g;
        const float* b_next = (l < 3) ? (norm_b + (l + 1) * DD) : final_b;
        gemm2_ln<<<MM / 32, 256, 0, stream>>>(
            ybf, wbf_out + (size_t)l * DD * HH, h, g_next, b_next,
            lnbuf, (l < 3) ? 1 : 0);
    }

    head_kernel<<<BB, 256, 0, stream>>>(h, final_g, final_b,
                                        head1_w, head1_b, head2_w, head2_b, outp);
}

// Round 12
// 502.823 us; speedup vs baseline: 1.0105x; 1.0105x over previous
//
#include <hip/hip_runtime.h>
#include <hip/hip_bf16.h>
#include <math.h>

// Model dims
#define BB 8
#define TT 1024
#define DD 256
#define HH 512
#define NN 16
#define RR 8
#define OUT_LEN 96
#define IN_DIM 32
#define MM (BB*TT)   // 8192 rows

// scan chunking (validated R10): 512 blocks/pass
#define SC 32
#define CC (TT/SC)   // 32

typedef unsigned short u16;
typedef unsigned int u32;
typedef __attribute__((ext_vector_type(8))) short short8;
typedef __attribute__((ext_vector_type(8))) unsigned short u16x8;
typedef __attribute__((ext_vector_type(4))) float float4v;

__device__ __forceinline__ u16 f2bf(float f) {
    __hip_bfloat16 h = __float2bfloat16(f);
    return *(u16*)&h;
}
__device__ __forceinline__ float bf2f(u16 u) {
    u32 v = ((u32)u) << 16;
    return *(float*)&v;
}

#define GLD_LDS16(src, dst) __builtin_amdgcn_global_load_lds( \
    (const __attribute__((address_space(1))) void*)(src),     \
    (__attribute__((address_space(3))) void*)(dst), 16, 0, 0)

// ---------------------------------------------------------------------------
// Embedding + PE + layer-0 LN (blocks 0..MM-1) | weight bf16 cvt (rest).
// (validated R10)
// ---------------------------------------------------------------------------
__global__ __launch_bounds__(256) void embed_ln_cvt_kernel(
    const float* __restrict__ x, const float* __restrict__ emb_w,
    const float* __restrict__ emb_b,
    const float* __restrict__ g, const float* __restrict__ b,
    float* __restrict__ h, u16* __restrict__ lnout,
    const float* __restrict__ w_in, u16* __restrict__ wbf_in,
    const float* __restrict__ w_out, u16* __restrict__ wbf_out, int nw)
{
    int bid = blockIdx.x;
    if (bid >= MM) {
        int i = (bid - MM) * 256 + threadIdx.x;
        if (i < nw) wbf_in[i] = f2bf(w_in[i]);
        else        wbf_out[i - nw] = f2bf(w_out[i - nw]);
        return;
    }

    int bt = bid;
    int d  = threadIdx.x;
    int t  = bt & (TT - 1);

    __shared__ float xs[IN_DIM];
    __shared__ float red[4], red2[4];
    if (threadIdx.x < IN_DIM) xs[threadIdx.x] = x[bt * IN_DIM + threadIdx.x];
    __syncthreads();

    const float* w = emb_w + d * IN_DIM;
    float acc = emb_b[d];
#pragma unroll
    for (int i = 0; i < IN_DIM; i++) acc = fmaf(xs[i], w[i], acc);

    int i2 = d & ~1;
    float div = expf(-(float)i2 * (logf(10000.0f) / (float)DD));
    float arg = (float)t * div;
    float pe = (d & 1) ? cosf(arg) : sinf(arg);
    float val = acc + pe;
    h[bt * DD + d] = val;

    float s = val;
#pragma unroll
    for (int o = 32; o > 0; o >>= 1) s += __shfl_down(s, o);
    int lane = d & 63, wave = d >> 6;
    if (lane == 0) red[wave] = s;
    __syncthreads();
    float mean = (red[0] + red[1] + red[2] + red[3]) * (1.0f / DD);

    float c = val - mean;
    float s2 = c * c;
#pragma unroll
    for (int o = 32; o > 0; o >>= 1) s2 += __shfl_down(s2, o);
    if (lane == 0) red2[wave] = s2;
    __syncthreads();
    float var = (red2[0] + red2[1] + red2[2] + red2[3]) * (1.0f / DD);

    lnout[bt * DD + d] = f2bf(c * rsqrtf(var + 1e-5f) * g[d] + b[d]);
}

// ---------------------------------------------------------------------------
// bf16 MFMA NT GEMM, BK=64 (validated R5-R10; R11's BK=128 regressed via
// LDS-occupancy cliff -- keep 24 KB / 4-6 blocks/CU).
// ---------------------------------------------------------------------------
template<int BM, int BN, int OUT_BF16>
__global__ __launch_bounds__(256) void gemm_bf16(
    const u16* __restrict__ A, const u16* __restrict__ B,
    void* __restrict__ Cv, int M, int N, int K, int addC)
{
    constexpr int BK = 64;
    constexpr int MT = BM / 32;
    constexpr int NT = BN / 32;
    static_assert(BN == 64, "B staging assumes BN==64");

    __shared__ __align__(16) u16 Al[8][BM][8];
    __shared__ __align__(16) u16 Bl[8][BN][8];

    const int tid = threadIdx.x;
    const int bm = blockIdx.y * BM;
    const int bn = blockIdx.x * BN;
    const int wid = tid >> 6, lane = tid & 63;
    const int wm = wid >> 1, wn = wid & 1;
    const int lq = lane >> 4, lm = lane & 15;

    float4v acc[MT][NT];
#pragma unroll
    for (int i = 0; i < MT; i++)
#pragma unroll
        for (int j = 0; j < NT; j++) acc[i][j] = (float4v){0.f, 0.f, 0.f, 0.f};

    for (int k0 = 0; k0 < K; k0 += BK) {
#pragma unroll
        for (int it = 0; it < (8 * BM) / 256; it++) {
            int c = it * 256 + tid;
            int q = c / BM, row = c % BM;
            GLD_LDS16(A + (size_t)(bm + row) * K + k0 + q * 8, &Al[q][row][0]);
        }
#pragma unroll
        for (int it = 0; it < (8 * BN) / 256; it++) {
            int c = it * 256 + tid;
            int q = c / BN, row = c % BN;
            GLD_LDS16(B + (size_t)(bn + row) * K + k0 + q * 8, &Bl[q][row][0]);
        }
        __syncthreads();

        short8 af[2][MT], bf[2][NT];
#pragma unroll
        for (int kk = 0; kk < 2; kk++) {
#pragma unroll
            for (int mt = 0; mt < MT; mt++)
                af[kk][mt] = *(const short8*)&Al[kk * 4 + lq][wm * (BM / 2) + mt * 16 + lm][0];
#pragma unroll
            for (int nt = 0; nt < NT; nt++)
                bf[kk][nt] = *(const short8*)&Bl[kk * 4 + lq][wn * (BN / 2) + nt * 16 + lm][0];
        }

#pragma unroll
        for (int kk = 0; kk < 2; kk++)
#pragma unroll
            for (int mt = 0; mt < MT; mt++)
#pragma unroll
                for (int nt = 0; nt < NT; nt++)
                    acc[mt][nt] = __builtin_amdgcn_mfma_f32_16x16x32_bf16(
                        af[kk][mt], bf[kk][nt], acc[mt][nt], 0, 0, 0);
        __syncthreads();
    }

#pragma unroll
    for (int mt = 0; mt < MT; mt++)
#pragma unroll
        for (int nt = 0; nt < NT; nt++) {
            int row0 = bm + wm * (BM / 2) + mt * 16 + lq * 4;
            int col  = bn + wn * (BN / 2) + nt * 16 + lm;
#pragma unroll
            for (int r = 0; r < 4; r++) {
                float vv = acc[mt][nt][r];
                if (OUT_BF16) {
                    ((u16*)Cv)[(size_t)(row0 + r) * N + col] = f2bf(vv);
                } else {
                    float* cp = (float*)Cv + (size_t)(row0 + r) * N + col;
                    if (addC) vv += *cp;
                    *cp = vv;
                }
            }
        }
}

// ---------------------------------------------------------------------------
// Out-projection GEMM + residual + next-layer LN, BK=64 (validated R9/R10)
// ---------------------------------------------------------------------------
__global__ __launch_bounds__(256) void gemm2_ln(
    const u16* __restrict__ A, const u16* __restrict__ B,
    float* __restrict__ h,
    const float* __restrict__ g, const float* __restrict__ bb,
    u16* __restrict__ lnout, int doLN)
{
    constexpr int BM = 32;
    __shared__ __align__(16) u16 Al[8][BM][8];   // 4 KB
    __shared__ __align__(16) u16 Bl[8][256][8];  // 32 KB
    __shared__ float rs[2][BM], qs[2][BM];

    const int tid = threadIdx.x;
    const int bm = blockIdx.x * BM;
    const int wid = tid >> 6, lane = tid & 63;
    const int wm = wid >> 1, wn = wid & 1;
    const int lq = lane >> 4, lm = lane & 15;

    float4v acc[8];
#pragma unroll
    for (int j = 0; j < 8; j++) acc[j] = (float4v){0.f, 0.f, 0.f, 0.f};

    for (int k0 = 0; k0 < 512; k0 += 64) {
        {
            int q = tid >> 5, row = tid & 31;
            GLD_LDS16(A + (size_t)(bm + row) * 512 + k0 + q * 8, &Al[q][row][0]);
        }
#pragma unroll
        for (int it = 0; it < 8; it++) {
            int c = it * 256 + tid;
            int q = c >> 8, row = c & 255;
            GLD_LDS16(B + (size_t)row * 512 + k0 + q * 8, &Bl[q][row][0]);
        }
        __syncthreads();

        short8 af[2], bf[2][8];
#pragma unroll
        for (int kk = 0; kk < 2; kk++) {
            af[kk] = *(const short8*)&Al[kk * 4 + lq][wm * 16 + lm][0];
#pragma unroll
            for (int nt = 0; nt < 8; nt++)
                bf[kk][nt] = *(const short8*)&Bl[kk * 4 + lq][wn * 128 + nt * 16 + lm][0];
        }
#pragma unroll
        for (int kk = 0; kk < 2; kk++)
#pragma unroll
            for (int nt = 0; nt < 8; nt++)
                acc[nt] = __builtin_amdgcn_mfma_f32_16x16x32_bf16(
                    af[kk], bf[kk][nt], acc[nt], 0, 0, 0);
        __syncthreads();
    }

    float val[4][8];
    float s1[4] = {0.f, 0.f, 0.f, 0.f}, s2[4] = {0.f, 0.f, 0.f, 0.f};
#pragma unroll
    for (int r = 0; r < 4; r++) {
        int row = bm + wm * 16 + lq * 4 + r;
#pragma unroll
        for (int nt = 0; nt < 8; nt++) {
            int col = wn * 128 + nt * 16 + lm;
            float v = acc[nt][r] + h[(size_t)row * DD + col];
            val[r][nt] = v;
            s1[r] += v;
            s2[r] = fmaf(v, v, s2[r]);
            h[(size_t)row * DD + col] = v;
        }
    }
#pragma unroll
    for (int r = 0; r < 4; r++) {
#pragma unroll
        for (int o = 1; o < 16; o <<= 1) {
            s1[r] += __shfl_xor(s1[r], o);
            s2[r] += __shfl_xor(s2[r], o);
        }
    }
    if (lm == 0) {
#pragma unroll
        for (int r = 0; r < 4; r++) {
            rs[wn][wm * 16 + lq * 4 + r] = s1[r];
            qs[wn][wm * 16 + lq * 4 + r] = s2[r];
        }
    }
    __syncthreads();

    if (doLN) {
#pragma unroll
        for (int r = 0; r < 4; r++) {
            int i = wm * 16 + lq * 4 + r;
            int row = bm + i;
            float mean = (rs[0][i] + rs[1][i]) * (1.0f / DD);
            float var  = (qs[0][i] + qs[1][i]) * (1.0f / DD) - mean * mean;
            float rstd = rsqrtf(var + 1e-5f);
#pragma unroll
            for (int nt = 0; nt < 8; nt++) {
                int col = wn * 128 + nt * 16 + lm;
                lnout[(size_t)row * DD + col] =
                    f2bf((val[r][nt] - mean) * rstd * g[col] + bb[col]);
            }
        }
    }
}

// ---------------------------------------------------------------------------
// Fused depthwise conv(k=3,pad1)+SiLU + dt1 (validated R7-R10)
// ---------------------------------------------------------------------------
__global__ __launch_bounds__(256) void conv_dt1_kernel(
    const u16* __restrict__ v, const float* __restrict__ cwg,
    const float* __restrict__ w1g, const float* __restrict__ b1g,
    u16* __restrict__ vsb, float* __restrict__ dtr)
{
    __shared__ float w1s[RR * 2 * 256];
    int tid = threadIdx.x;
    {
        int lane = tid & 63, rc = tid >> 6;
#pragma unroll
        for (int i = 0; i < 4; i++) {
            int rci = rc + i * 4;
            int r = rci >> 1, jc = rci & 1;
            float4 wv = *(const float4*)(w1g + r * HH + lane * 8 + jc * 4);
            *(float4*)&w1s[rci * 256 + lane * 4] = wv;
        }
    }
    __syncthreads();

    int wave = tid >> 6, lane = tid & 63;
    int m = blockIdx.x * 4 + wave;
    int t = m & (TT - 1);
    int h0 = lane * 8;

    const u16* vrow = v + (size_t)m * HH + h0;
    u16x8 x0 = *(const u16x8*)vrow;
    u16x8 xm = (t > 0)      ? *(const u16x8*)(vrow - HH) : (u16x8)(0);
    u16x8 xp = (t < TT - 1) ? *(const u16x8*)(vrow + HH) : (u16x8)(0);

    const float* wp = cwg + h0 * 3;
    float a[8];
    u16x8 o;
#pragma unroll
    for (int j = 0; j < 8; j++) {
        float s = wp[j * 3] * bf2f(xm[j]);
        s = fmaf(wp[j * 3 + 1], bf2f(x0[j]), s);
        s = fmaf(wp[j * 3 + 2], bf2f(xp[j]), s);
        s = s / (1.0f + __expf(-s));
        a[j] = s;
        o[j] = f2bf(s);
    }
    *(u16x8*)(vsb + (size_t)m * HH + h0) = o;

    float acc[RR];
#pragma unroll
    for (int r = 0; r < RR; r++) {
        float4 wlo = *(const float4*)&w1s[(r * 2 + 0) * 256 + lane * 4];
        float4 whi = *(const float4*)&w1s[(r * 2 + 1) * 256 + lane * 4];
        float s = a[0] * wlo.x;
        s = fmaf(a[1], wlo.y, s);
        s = fmaf(a[2], wlo.z, s);
        s = fmaf(a[3], wlo.w, s);
        s = fmaf(a[4], whi.x, s);
        s = fmaf(a[5], whi.y, s);
        s = fmaf(a[6], whi.z, s);
        s = fmaf(a[7], whi.w, s);
        acc[r] = s;
    }
#pragma unroll
    for (int r = 0; r < RR; r++) {
#pragma unroll
        for (int o2 = 1; o2 < 64; o2 <<= 1) acc[r] += __shfl_xor(acc[r], o2);
    }
    if (lane == 0) {
#pragma unroll
        for (int r = 0; r < RR; r++) acc[r] = fmaxf(acc[r] + b1g[r], 0.0f);
        *(float4*)(dtr + (size_t)m * RR)     = make_float4(acc[0], acc[1], acc[2], acc[3]);
        *(float4*)(dtr + (size_t)m * RR + 4) = make_float4(acc[4], acc[5], acc[6], acc[7]);
    }
}

// ---------------------------------------------------------------------------
__device__ __forceinline__ float softplus_f(float s) {
    return (s > 20.0f) ? s : __logf(1.0f + __expf(s));
}

// ---------------------------------------------------------------------------
// Scan pass1 (validated R10; bf16 Lst)
// ---------------------------------------------------------------------------
__global__ __launch_bounds__(256) void scan_pass1(
    const u16* __restrict__ vs, const float* __restrict__ dtr,
    const float* __restrict__ dt2_w, const float* __restrict__ dt2_b,
    const float* __restrict__ A_p,
    u16* __restrict__ Lst, float* __restrict__ sdt)
{
    int h = blockIdx.x * 256 + threadIdx.x;
    int c = blockIdx.y;
    int b = blockIdx.z;

    float A[NN], invA[NN], st[NN];
    const float* ap = A_p + h * NN;
#pragma unroll
    for (int n = 0; n < NN; n++) {
        float a = -__expf(ap[n]);
        A[n] = a; invA[n] = 1.0f / a; st[n] = 0.0f;
    }
    float w2[RR];
#pragma unroll
    for (int r = 0; r < RR; r++) w2[r] = dt2_w[h * RR + r];
    float b2 = dt2_b[h];

    const u16*   vbase = vs  + ((size_t)b * TT + (size_t)c * SC) * HH + h;
    const float* drow  = dtr + ((size_t)b * TT + (size_t)c * SC) * RR;

    float dr[RR];
#pragma unroll
    for (int r = 0; r < RR; r++) dr[r] = drow[r];

    float s_dt = 0.0f;
#pragma unroll 2
    for (int t = 0; t < SC; t++) {
        float drn[RR];
        if (t + 1 < SC) {
#pragma unroll
            for (int r = 0; r < RR; r++) drn[r] = drow[(t + 1) * RR + r];
        }
        float s = b2;
#pragma unroll
        for (int r = 0; r < RR; r++) s = fmaf(dr[r], w2[r], s);
        float dt = softplus_f(s);
        float xv = bf2f(vbase[(size_t)t * HH]);
        s_dt += dt;
#pragma unroll
        for (int n = 0; n < NN; n++) {
            float e  = __expf(A[n] * dt);
            float dB = (e - 1.0f) * invA[n] * dt;
            st[n] = fmaf(e, st[n], dB * xv);
        }
#pragma unroll
        for (int r = 0; r < RR; r++) dr[r] = drn[r];
    }

    size_t base = (((size_t)c * BB + b) * HH + h) * NN;
    u16x8 lo, hi;
#pragma unroll
    for (int n = 0; n < 8; n++) { lo[n] = f2bf(st[n]); hi[n] = f2bf(st[n + 8]); }
    *(u16x8*)(Lst + base)     = lo;
    *(u16x8*)(Lst + base + 8) = hi;
    sdt[((size_t)c * BB + b) * HH + h] = s_dt;
}

// ---------------------------------------------------------------------------
// Carry (validated R10 sequential form; R11's batched arrays regressed)
// ---------------------------------------------------------------------------
__global__ __launch_bounds__(256) void scan_carry(
    const float* __restrict__ A_p, const float* __restrict__ sdt,
    u16* __restrict__ Lst)
{
    int i = blockIdx.x * 256 + threadIdx.x;   // (b*HH+h)*NN+n
    int n  = i & (NN - 1);
    int bh = i >> 4;
    int h  = bh & (HH - 1);
    int b  = bh >> 9;

    float A = -__expf(A_p[h * NN + n]);
    float E = 0.0f;
    for (int c = 0; c < CC; c++) {
        size_t sidx = ((size_t)c * BB + b) * HH + h;
        float P = __expf(A * sdt[sidx]);
        size_t lidx = sidx * NN + n;
        float Lc = bf2f(Lst[lidx]);
        Lst[lidx] = f2bf(E);
        E = fmaf(P, E, Lc);
    }
}

// ---------------------------------------------------------------------------
// Scan pass2 (validated R10; bf16 carry)
// ---------------------------------------------------------------------------
__global__ __launch_bounds__(256) void scan_pass2(
    const u16* __restrict__ vs,
    const float* __restrict__ dtr,
    const float* __restrict__ dt2_w,
    const float* __restrict__ dt2_b,
    const float* __restrict__ A_p, const float* __restrict__ D_p,
    const u16* __restrict__ carry,
    u16* __restrict__ y)
{
    int h = blockIdx.x * 256 + threadIdx.x;
    int c = blockIdx.y;
    int b = blockIdx.z;

    float A[NN], invA[NN], Ap[NN], st[NN];
    const float* app = A_p + h * NN;
    size_t cbase = (((size_t)c * BB + b) * HH + h) * NN;
    {
        u16x8 lo = *(const u16x8*)(carry + cbase);
        u16x8 hi = *(const u16x8*)(carry + cbase + 8);
#pragma unroll
        for (int n = 0; n < 8; n++) { st[n] = bf2f(lo[n]); st[n + 8] = bf2f(hi[n]); }
    }
#pragma unroll
    for (int n = 0; n < NN; n++) {
        float apv = app[n];
        Ap[n] = apv;
        float a = -__expf(apv);
        A[n] = a; invA[n] = 1.0f / a;
    }
    float w2[RR];
#pragma unroll
    for (int r = 0; r < RR; r++) w2[r] = dt2_w[h * RR + r];
    float b2 = dt2_b[h];
    float Dp = D_p[h];

    const u16*   vbase = vs  + ((size_t)b * TT + (size_t)c * SC) * HH + h;
    const float* drow  = dtr + ((size_t)b * TT + (size_t)c * SC) * RR;
    u16*         ybase = y   + ((size_t)b * TT + (size_t)c * SC) * HH + h;

    float dr[RR];
#pragma unroll
    for (int r = 0; r < RR; r++) dr[r] = drow[r];

#pragma unroll 2
    for (int t = 0; t < SC; t++) {
        float drn[RR];
        if (t + 1 < SC) {
#pragma unroll
            for (int r = 0; r < RR; r++) drn[r] = drow[(t + 1) * RR + r];
        }
        float s = b2;
#pragma unroll
        for (int r = 0; r < RR; r++) s = fmaf(dr[r], w2[r], s);
        float dt = softplus_f(s);
        float xv = bf2f(vbase[(size_t)t * HH]);
        float acc = Dp * xv;
#pragma unroll
        for (int n = 0; n < NN; n++) {
            float e  = __expf(A[n] * dt);
            float dB = (e - 1.0f) * invA[n] * dt;
            st[n] = fmaf(e, st[n], dB * xv);
            acc = fmaf(st[n], Ap[n], acc);
        }
        ybase[(size_t)t * HH] = f2bf(acc);
#pragma unroll
        for (int r = 0; r < RR; r++) dr[r] = drn[r];
    }
}

// ---------------------------------------------------------------------------
// Head: final LN on last token, head1+silu, head2. One block per batch.
// ---------------------------------------------------------------------------
__global__ __launch_bounds__(256) void head_kernel(
    const float* __restrict__ h,
    const float* __restrict__ fg, const float* __restrict__ fb,
    const float* __restrict__ w1, const float* __restrict__ b1,
    const float* __restrict__ w2, const float* __restrict__ b2,
    float* __restrict__ out)
{
    int b = blockIdx.x;
    int d = threadIdx.x;
    __shared__ float hn[DD], s1[DD];
    __shared__ float red[4];

    float v = h[((size_t)b * TT + (TT - 1)) * DD + d];

    float s = v;
#pragma unroll
    for (int o = 32; o > 0; o >>= 1) s += __shfl_down(s, o);
    int lane = d & 63, wave = d >> 6;
    if (lane == 0) red[wave] = s;
    __syncthreads();
    float mean = (red[0] + red[1] + red[2] + red[3]) * (1.0f / DD);
    __syncthreads();

    float c = v - mean;
    float s2 = c * c;
#pragma unroll
    for (int o = 32; o > 0; o >>= 1) s2 += __shfl_down(s2, o);
    if (lane == 0) red[wave] = s2;
    __syncthreads();
    float var = (red[0] + red[1] + red[2] + red[3]) * (1.0f / DD);

    hn[d] = c * rsqrtf(var + 1e-5f) * fg[d] + fb[d];
    __syncthreads();

    float a1 = b1[d];
    const float* w1r = w1 + d * DD;
#pragma unroll 8
    for (int k = 0; k < DD; k++) a1 = fmaf(hn[k], w1r[k], a1);
    s1[d] = a1 / (1.0f + __expf(-a1));
    __syncthreads();

    if (d < OUT_LEN) {
        float a2 = b2[d];
        const float* w2r = w2 + d * DD;
#pragma unroll 8
        for (int k = 0; k < DD; k++) a2 = fmaf(s1[k], w2r[k], a2);
        out[b * OUT_LEN + d] = a2;
    }
}

// ---------------------------------------------------------------------------
extern "C" void kernel_launch(void* const* d_in, const int* in_sizes, int n_in,
                              void* d_out, int out_size, void* d_ws, size_t ws_size,
                              hipStream_t stream)
{
    (void)in_sizes; (void)n_in; (void)out_size; (void)ws_size;

    const float* x       = (const float*)d_in[0];
    const float* emb_w   = (const float*)d_in[1];
    const float* emb_b   = (const float*)d_in[2];
    const float* norm_g  = (const float*)d_in[3];
    const float* norm_b  = (const float*)d_in[4];
    const float* in_w    = (const float*)d_in[5];
    const float* conv_w  = (const float*)d_in[6];
    const float* A_p     = (const float*)d_in[7];
    const float* D_p     = (const float*)d_in[8];
    const float* dt1_w   = (const float*)d_in[9];
    const float* dt1_b   = (const float*)d_in[10];
    const float* dt2_w   = (const float*)d_in[11];
    const float* dt2_b   = (const float*)d_in[12];
    const float* out_w   = (const float*)d_in[13];
    const float* final_g = (const float*)d_in[14];
    const float* final_b = (const float*)d_in[15];
    const float* head1_w = (const float*)d_in[16];
    const float* head1_b = (const float*)d_in[17];
    const float* head2_w = (const float*)d_in[18];
    const float* head2_b = (const float*)d_in[19];
    float* outp = (float*)d_out;

    char* ws = (char*)d_ws;
    float* h     = (float*)ws;                ws += (size_t)MM * DD * 4;   // fp32 residual
    u16*   vbf   = (u16*)ws;                  ws += (size_t)MM * HH * 2;   // gemm1 out
    u16*   vsb   = (u16*)ws;                  ws += (size_t)MM * HH * 2;   // conv+silu
    u16*   ybf   = (u16*)ws;                  ws += (size_t)MM * HH * 2;   // scan y
    u16*   lnbuf = (u16*)ws;                  ws += (size_t)MM * DD * 2;   // LN out
    float* dtr   = (float*)ws;                ws += (size_t)MM * RR * 4;
    u16*   Lst   = (u16*)ws;                  ws += (size_t)CC * BB * HH * NN * 2;  // bf16
    float* sdt   = (float*)ws;                ws += (size_t)CC * BB * HH * 4;
    u16*   wbf_in  = (u16*)ws;                ws += (size_t)4 * HH * DD * 2;
    u16*   wbf_out = (u16*)ws;                ws += (size_t)4 * DD * HH * 2;

    const int NW = 4 * HH * DD;
    embed_ln_cvt_kernel<<<MM + (2 * NW) / 256, 256, 0, stream>>>(
        x, emb_w, emb_b, norm_g, norm_b, h, lnbuf,
        in_w, wbf_in, out_w, wbf_out, NW);

    for (int l = 0; l < 4; l++) {
        gemm_bf16<128, 64, 1><<<dim3(HH / 64, MM / 128), 256, 0, stream>>>(
            lnbuf, wbf_in + (size_t)l * HH * DD, vbf, MM, HH, DD, 0);
        conv_dt1_kernel<<<MM / 4, 256, 0, stream>>>(
            vbf, conv_w + (size_t)l * HH * 3,
            dt1_w + (size_t)l * RR * HH, dt1_b + l * RR, vsb, dtr);

        scan_pass1<<<dim3(HH / 256, CC, BB), 256, 0, stream>>>(
            vsb, dtr, dt2_w + (size_t)l * HH * RR, dt2_b + l * HH,
            A_p + (size_t)l * HH * NN, Lst, sdt);
        scan_carry<<<(BB * HH * NN) / 256, 256, 0, stream>>>(
            A_p + (size_t)l * HH * NN, sdt, Lst);
        scan_pass2<<<dim3(HH / 256, CC, BB), 256, 0, stream>>>(
            vsb, dtr, dt2_w + (size_t)l * HH * RR, dt2_b + l * HH,
            A_p + (size_t)l * HH * NN, D_p + l * HH, Lst, ybf);

        const float* g_next = (l < 3) ? (norm_g + (l + 1) * DD) : final_g;
        const float* b_next = (l < 3) ? (norm_b + (l + 1) * DD) : final_b;
        gemm2_ln<<<MM / 32, 256, 0, stream>>>(
            ybf, wbf_out + (size_t)l * DD * HH, h, g_next, b_next,
            lnbuf, (l < 3) ? 1 : 0);
    }

    head_kernel<<<BB, 256, 0, stream>>>(h, final_g, final_b,
                                        head1_w, head1_b, head2_w, head2_b, outp);
}